// Round 2
// baseline (771.884 us; speedup 1.0000x reference)
//
#include <hip/hip_runtime.h>
#include <hip/hip_bf16.h>
#include <stdint.h>

// ---------------------------------------------------------------------------
// DoubleStreamBlock (Flux MMDiT) on MI355X. IO = float32; compute bf16 MFMA.
// NH=16 HD=64 HID=1024 MLP=4096, img L=2048, txt L=512, Lattn=2560.
// ---------------------------------------------------------------------------

#define NHEAD 16
#define HDIM  64
#define HIDD  1024
#define MLPD  4096
#define L_IMG 2048
#define L_TXT 512
#define L_TOT 2560
#define EPSV  1e-6f

typedef __attribute__((ext_vector_type(8))) __bf16 bf16x8;
typedef __attribute__((ext_vector_type(4))) float  f32x4;

__device__ __forceinline__ float u2f(uint16_t u) {
    uint32_t i = (uint32_t)u << 16;
    float f; __builtin_memcpy(&f, &i, 4);
    return f;
}
__device__ __forceinline__ uint16_t f2u(float f) {
    uint32_t i; __builtin_memcpy(&i, &f, 4);
    uint32_t r = (i + 0x7fffu + ((i >> 16) & 1u)) >> 16;   // RNE
    return (uint16_t)r;
}
__device__ __forceinline__ float gelu_tanh(float x) {
    float x3 = x * x * x;
    float t  = tanhf(0.7978845608028654f * (x + 0.044715f * x3));
    return 0.5f * x * (1.f + t);
}

// ---------------------------------------------------------------------------
// Transpose + cast: f32 [K][N] -> bf16 [N][K]  (64x64 LDS tiles)
// ---------------------------------------------------------------------------
__global__ __launch_bounds__(256) void transpose_f32_bf16(const float* __restrict__ in,
                                                          uint16_t* __restrict__ out,
                                                          int K, int N) {
    __shared__ float tile[64][65];
    const int t  = threadIdx.x;
    const int c0 = blockIdx.x * 64;   // col tile (N dim)
    const int r0 = blockIdx.y * 64;   // row tile (K dim)
#pragma unroll
    for (int p = 0; p < 4; p++) {
        int row  = p * 16 + (t >> 4);
        int col4 = (t & 15) * 4;
        float4 v = *(const float4*)(in + (size_t)(r0 + row) * N + c0 + col4);
        tile[row][col4 + 0] = v.x; tile[row][col4 + 1] = v.y;
        tile[row][col4 + 2] = v.z; tile[row][col4 + 3] = v.w;
    }
    __syncthreads();
#pragma unroll
    for (int p = 0; p < 4; p++) {
        int row  = p * 16 + (t >> 4);   // output row = original col
        int col4 = (t & 15) * 4;
        ushort4 v;
        v.x = f2u(tile[col4 + 0][row]); v.y = f2u(tile[col4 + 1][row]);
        v.z = f2u(tile[col4 + 2][row]); v.w = f2u(tile[col4 + 3][row]);
        *(ushort4*)(out + (size_t)(c0 + row) * K + r0 + col4) = v;
    }
}

// ---------------------------------------------------------------------------
// mod GEMV: mod[j] = dot(silu(vec), W[:,j]) + b[j],  j in [0,6144)
// ---------------------------------------------------------------------------
__global__ __launch_bounds__(256) void mod_gemv_kernel(const float* __restrict__ vec,
                                                       const float* __restrict__ w,
                                                       const float* __restrict__ b,
                                                       float* __restrict__ mod) {
    __shared__ float s[HIDD];
    const int t = threadIdx.x;
    for (int i = t; i < HIDD; i += 256) {
        float x = vec[i];
        s[i] = x / (1.f + __expf(-x));
    }
    __syncthreads();
    const int j = blockIdx.x * 256 + t;
    float acc = 0.f;
#pragma unroll 8
    for (int k = 0; k < HIDD; k++) acc += s[k] * w[(size_t)k * 6144 + j];
    mod[j] = acc + b[j];
}

// ---------------------------------------------------------------------------
// Fused LayerNorm + modulate: xm = (1+sc)*LN(x) + sh   (bf16 out, f32 in)
// One block per row of 1024.
// ---------------------------------------------------------------------------
__global__ __launch_bounds__(256) void ln_mod_kernel(const float* __restrict__ x,
                                                     const float* __restrict__ mod,
                                                     int scOff, int shOff,
                                                     uint16_t* __restrict__ xm) {
    __shared__ float red[8];
    const int row = blockIdx.x, t = threadIdx.x;
    const size_t base = (size_t)row * HIDD + t * 4;
    float4 u = *(const float4*)(x + base);
    float v[4] = {u.x, u.y, u.z, u.w};
    float s = v[0] + v[1] + v[2] + v[3];
    float q = v[0]*v[0] + v[1]*v[1] + v[2]*v[2] + v[3]*v[3];
#pragma unroll
    for (int o = 32; o; o >>= 1) { s += __shfl_down(s, o); q += __shfl_down(q, o); }
    if ((t & 63) == 0) { red[t >> 6] = s; red[4 + (t >> 6)] = q; }
    __syncthreads();
    s = red[0] + red[1] + red[2] + red[3];
    q = red[4] + red[5] + red[6] + red[7];
    const float mu  = s * (1.f / HIDD);
    const float var = q * (1.f / HIDD) - mu * mu;
    const float rs  = rsqrtf(var + EPSV);
    ushort4 o;
    {
        int col = t * 4;
        float y0 = (v[0] - mu) * rs, y1 = (v[1] - mu) * rs;
        float y2 = (v[2] - mu) * rs, y3 = (v[3] - mu) * rs;
        o.x = f2u(y0 + mod[scOff + col + 0] * y0 + mod[shOff + col + 0]);
        o.y = f2u(y1 + mod[scOff + col + 1] * y1 + mod[shOff + col + 1]);
        o.z = f2u(y2 + mod[scOff + col + 2] * y2 + mod[shOff + col + 2]);
        o.w = f2u(y3 + mod[scOff + col + 3] * y3 + mod[shOff + col + 3]);
    }
    *(ushort4*)(xm + base) = o;
}

// ---------------------------------------------------------------------------
// m97-style bf16 GEMM: C[M][N] = A[M][K] * BT[N][K]^T, 128x128 tile, BK=32.
// EPI: 0 = store bf16
//      1 = gelu(acc+bias) -> bf16
//      2 = f32 out = f32resid + gate[col]*(acc+bias)
//      3 = f32 out = f32resid + gate[col]*(acc+bias)  (final output)
// ---------------------------------------------------------------------------
template <int EPI>
__global__ __launch_bounds__(256, 2) void gemm_kernel(
        const uint16_t* __restrict__ A, const uint16_t* __restrict__ BT,
        int M, int N, int K,
        const float* __restrict__ bias,
        const float* __restrict__ gate,
        const float* __restrict__ resid,
        void* __restrict__ C) {
    __shared__ uint16_t As[128 * 32];
    __shared__ uint16_t Bs[128 * 32];
    const int t = threadIdx.x;
    const int w = t >> 6, l = t & 63;
    const int lr = l & 15, lg = l >> 4;
    const int m0 = blockIdx.y * 128, n0 = blockIdx.x * 128;
    const int srow = l >> 2, scol = (l & 3) * 8;
    const int c0 = w * 2;
    const int wr = (w >> 1) * 64, wc = (w & 1) * 64;

    const f32x4 z4 = {0.f, 0.f, 0.f, 0.f};
    f32x4 acc[4][4];
#pragma unroll
    for (int i = 0; i < 4; i++)
#pragma unroll
        for (int j = 0; j < 4; j++) acc[i][j] = z4;

    for (int kt = 0; kt < K; kt += 32) {
        __syncthreads();
#pragma unroll
        for (int i = 0; i < 2; i++) {
            const int c = c0 + i;
            const uint16_t* ga = A  + (size_t)(m0 + c * 16 + srow) * K + kt + scol;
            const uint16_t* gb = BT + (size_t)(n0 + c * 16 + srow) * K + kt + scol;
            __builtin_amdgcn_global_load_lds(
                (__attribute__((address_space(1))) void*)ga,
                (__attribute__((address_space(3))) void*)(As + c * 512), 16, 0, 0);
            __builtin_amdgcn_global_load_lds(
                (__attribute__((address_space(1))) void*)gb,
                (__attribute__((address_space(3))) void*)(Bs + c * 512), 16, 0, 0);
        }
        __syncthreads();
        bf16x8 af[4], bfr[4];
#pragma unroll
        for (int mi = 0; mi < 4; mi++)
            af[mi] = *(const bf16x8*)(As + (wr + mi * 16 + lr) * 32 + lg * 8);
#pragma unroll
        for (int nj = 0; nj < 4; nj++)
            bfr[nj] = *(const bf16x8*)(Bs + (wc + nj * 16 + lr) * 32 + lg * 8);
#pragma unroll
        for (int mi = 0; mi < 4; mi++)
#pragma unroll
            for (int nj = 0; nj < 4; nj++)
                acc[mi][nj] = __builtin_amdgcn_mfma_f32_16x16x32_bf16(
                    af[mi], bfr[nj], acc[mi][nj], 0, 0, 0);
    }

#pragma unroll
    for (int mi = 0; mi < 4; mi++)
#pragma unroll
        for (int nj = 0; nj < 4; nj++) {
            const int col = n0 + wc + nj * 16 + lr;
            float bv = 0.f, gv = 0.f;
            if (EPI != 0) bv = bias[col];
            if (EPI == 2 || EPI == 3) gv = gate[col];
#pragma unroll
            for (int j = 0; j < 4; j++) {
                const int row = m0 + wr + mi * 16 + lg * 4 + j;
                const size_t idx = (size_t)row * N + col;
                float v = acc[mi][nj][j];
                if (EPI == 0) {
                    ((uint16_t*)C)[idx] = f2u(v);
                } else if (EPI == 1) {
                    ((uint16_t*)C)[idx] = f2u(gelu_tanh(v + bv));
                } else {
                    ((float*)C)[idx] = resid[idx] + gv * (v + bv);
                }
            }
        }
}

// ---------------------------------------------------------------------------
// RMS-norm q,k (per head of 64) + scatter qkv row -> head-major Q/K/V (bf16).
// Q gets the 1/sqrt(HD)=0.125 attention scale folded in.
// ---------------------------------------------------------------------------
__global__ __launch_bounds__(256) void rms_scatter_kernel(
        const uint16_t* __restrict__ qkv, int L, int glOff,
        const float* __restrict__ qs, const float* __restrict__ ks,
        uint16_t* __restrict__ Q, uint16_t* __restrict__ Kb, uint16_t* __restrict__ V) {
    const int row = blockIdx.x;
    const int t = threadIdx.x;
    const int head = t >> 4, d0 = (t & 15) * 4;
    const uint16_t* base = qkv + (size_t)row * 3072;
    const size_t obase = ((size_t)head * L_TOT + (glOff + row)) * HDIM + d0;
    // Q
    {
        ushort4 u = *(const ushort4*)(base + head * HDIM + d0);
        float v0 = u2f(u.x), v1 = u2f(u.y), v2 = u2f(u.z), v3 = u2f(u.w);
        float ss = v0*v0 + v1*v1 + v2*v2 + v3*v3;
        ss += __shfl_xor(ss, 1); ss += __shfl_xor(ss, 2);
        ss += __shfl_xor(ss, 4); ss += __shfl_xor(ss, 8);
        float inv = rsqrtf(ss * (1.f / HDIM) + EPSV) * 0.125f;
        ushort4 o;
        o.x = f2u(v0 * inv * qs[d0 + 0]);
        o.y = f2u(v1 * inv * qs[d0 + 1]);
        o.z = f2u(v2 * inv * qs[d0 + 2]);
        o.w = f2u(v3 * inv * qs[d0 + 3]);
        *(ushort4*)(Q + obase) = o;
    }
    // K
    {
        ushort4 u = *(const ushort4*)(base + HIDD + head * HDIM + d0);
        float v0 = u2f(u.x), v1 = u2f(u.y), v2 = u2f(u.z), v3 = u2f(u.w);
        float ss = v0*v0 + v1*v1 + v2*v2 + v3*v3;
        ss += __shfl_xor(ss, 1); ss += __shfl_xor(ss, 2);
        ss += __shfl_xor(ss, 4); ss += __shfl_xor(ss, 8);
        float inv = rsqrtf(ss * (1.f / HDIM) + EPSV);
        ushort4 o;
        o.x = f2u(v0 * inv * ks[d0 + 0]);
        o.y = f2u(v1 * inv * ks[d0 + 1]);
        o.z = f2u(v2 * inv * ks[d0 + 2]);
        o.w = f2u(v3 * inv * ks[d0 + 3]);
        *(ushort4*)(Kb + obase) = o;
    }
    // V (passthrough)
    {
        ushort4 u = *(const ushort4*)(base + 2 * HIDD + head * HDIM + d0);
        *(ushort4*)(V + obase) = u;
    }
}

// ---------------------------------------------------------------------------
// Flash attention: block = 4 waves x 32 q-rows, 32-key tiles, online softmax.
// Q/K/V head-major [h][L_TOT][64] bf16 (Q pre-scaled by 0.125).
// out: [L_TOT][1024] bf16 (heads reassembled).
// ---------------------------------------------------------------------------
__global__ __launch_bounds__(256) void attn_kernel(const uint16_t* __restrict__ Q,
                                                   const uint16_t* __restrict__ Kg,
                                                   const uint16_t* __restrict__ Vg,
                                                   uint16_t* __restrict__ out) {
    __shared__ uint16_t P[4][32][32];
    const int t = threadIdx.x;
    const int w = t >> 6, l = t & 63;
    const int lr = l & 15, lg = l >> 4;
    const int h = blockIdx.y;
    const int q0 = blockIdx.x * 128 + w * 32;
    const uint16_t* Qh = Q  + (size_t)h * L_TOT * HDIM;
    const uint16_t* Kh = Kg + (size_t)h * L_TOT * HDIM;
    const uint16_t* Vh = Vg + (size_t)h * L_TOT * HDIM;

    bf16x8 qf[2][2];
#pragma unroll
    for (int mi = 0; mi < 2; mi++)
#pragma unroll
        for (int ks = 0; ks < 2; ks++)
            qf[mi][ks] = *(const bf16x8*)(Qh + (size_t)(q0 + mi * 16 + lr) * HDIM + ks * 32 + lg * 8);

    const f32x4 z4 = {0.f, 0.f, 0.f, 0.f};
    f32x4 of[2][4];
    float mrun[2][4], lrun[2][4];
#pragma unroll
    for (int mi = 0; mi < 2; mi++) {
#pragma unroll
        for (int nj = 0; nj < 4; nj++) of[mi][nj] = z4;
#pragma unroll
        for (int j = 0; j < 4; j++) { mrun[mi][j] = -1e30f; lrun[mi][j] = 0.f; }
    }

    for (int k0 = 0; k0 < L_TOT; k0 += 32) {
        f32x4 sf[2][2];
        sf[0][0] = z4; sf[0][1] = z4; sf[1][0] = z4; sf[1][1] = z4;
#pragma unroll
        for (int nj = 0; nj < 2; nj++)
#pragma unroll
            for (int ks = 0; ks < 2; ks++) {
                bf16x8 kf = *(const bf16x8*)(Kh + (size_t)(k0 + nj * 16 + lr) * HDIM + ks * 32 + lg * 8);
                sf[0][nj] = __builtin_amdgcn_mfma_f32_16x16x32_bf16(qf[0][ks], kf, sf[0][nj], 0, 0, 0);
                sf[1][nj] = __builtin_amdgcn_mfma_f32_16x16x32_bf16(qf[1][ks], kf, sf[1][nj], 0, 0, 0);
            }
#pragma unroll
        for (int mi = 0; mi < 2; mi++) {
            float mt[4], corr[4], p0[4], p1[4], rs[4];
#pragma unroll
            for (int j = 0; j < 4; j++) mt[j] = fmaxf(sf[mi][0][j], sf[mi][1][j]);
#pragma unroll
            for (int o = 8; o; o >>= 1) {
#pragma unroll
                for (int j = 0; j < 4; j++) mt[j] = fmaxf(mt[j], __shfl_xor(mt[j], o));
            }
#pragma unroll
            for (int j = 0; j < 4; j++) {
                float mn = fmaxf(mrun[mi][j], mt[j]);
                corr[j] = __expf(mrun[mi][j] - mn);
                mrun[mi][j] = mn;
                p0[j] = __expf(sf[mi][0][j] - mn);
                p1[j] = __expf(sf[mi][1][j] - mn);
                rs[j] = p0[j] + p1[j];
            }
#pragma unroll
            for (int o = 8; o; o >>= 1) {
#pragma unroll
                for (int j = 0; j < 4; j++) rs[j] += __shfl_xor(rs[j], o);
            }
#pragma unroll
            for (int j = 0; j < 4; j++) lrun[mi][j] = lrun[mi][j] * corr[j] + rs[j];
#pragma unroll
            for (int nj = 0; nj < 4; nj++)
#pragma unroll
                for (int j = 0; j < 4; j++) of[mi][nj][j] *= corr[j];
#pragma unroll
            for (int j = 0; j < 4; j++) {
                P[w][mi * 16 + lg * 4 + j][lr]      = f2u(p0[j]);
                P[w][mi * 16 + lg * 4 + j][16 + lr] = f2u(p1[j]);
            }
        }
        bf16x8 pa0 = *(const bf16x8*)&P[w][lr][lg * 8];
        bf16x8 pa1 = *(const bf16x8*)&P[w][16 + lr][lg * 8];
#pragma unroll
        for (int nj = 0; nj < 4; nj++) {
            union { uint16_t u[8]; bf16x8 v; } vf;
#pragma unroll
            for (int j = 0; j < 8; j++)
                vf.u[j] = Vh[(size_t)(k0 + lg * 8 + j) * HDIM + nj * 16 + lr];
            of[0][nj] = __builtin_amdgcn_mfma_f32_16x16x32_bf16(pa0, vf.v, of[0][nj], 0, 0, 0);
            of[1][nj] = __builtin_amdgcn_mfma_f32_16x16x32_bf16(pa1, vf.v, of[1][nj], 0, 0, 0);
        }
    }
#pragma unroll
    for (int mi = 0; mi < 2; mi++)
#pragma unroll
        for (int j = 0; j < 4; j++) {
            float inv = 1.f / lrun[mi][j];
            size_t rbase = (size_t)(q0 + mi * 16 + lg * 4 + j) * HIDD + h * HDIM;
#pragma unroll
            for (int nj = 0; nj < 4; nj++)
                out[rbase + nj * 16 + lr] = f2u(of[mi][nj][j] * inv);
        }
}

// ---------------------------------------------------------------------------
// host launcher
// ---------------------------------------------------------------------------
extern "C" void kernel_launch(void* const* d_in, const int* in_sizes, int n_in,
                              void* d_out, int out_size, void* d_ws, size_t ws_size,
                              hipStream_t stream) {
    const float* img        = (const float*)d_in[0];
    const float* txt        = (const float*)d_in[1];
    const float* vec        = (const float*)d_in[2];
    const float* img_mod_w  = (const float*)d_in[3];
    const float* img_mod_b  = (const float*)d_in[4];
    const float* txt_mod_w  = (const float*)d_in[5];
    const float* txt_mod_b  = (const float*)d_in[6];
    const float* img_qkv_w  = (const float*)d_in[7];
    const float* img_q_s    = (const float*)d_in[8];
    const float* img_k_s    = (const float*)d_in[9];
    const float* img_proj_w = (const float*)d_in[10];
    const float* img_proj_b = (const float*)d_in[11];
    const float* img_mlp_w1 = (const float*)d_in[12];
    const float* img_mlp_b1 = (const float*)d_in[13];
    const float* img_mlp_w2 = (const float*)d_in[14];
    const float* img_mlp_b2 = (const float*)d_in[15];
    const float* txt_qkv_w  = (const float*)d_in[16];
    const float* txt_q_s    = (const float*)d_in[17];
    const float* txt_k_s    = (const float*)d_in[18];
    const float* txt_proj_w = (const float*)d_in[19];
    const float* txt_proj_b = (const float*)d_in[20];
    const float* txt_mlp_w1 = (const float*)d_in[21];
    const float* txt_mlp_b1 = (const float*)d_in[22];
    const float* txt_mlp_w2 = (const float*)d_in[23];
    const float* txt_mlp_b2 = (const float*)d_in[24];

    float* out_img = (float*)d_out;
    float* out_txt = out_img + (size_t)L_IMG * HIDD;

    char* ws = (char*)d_ws;
    size_t off = 0;
    auto alloc = [&](size_t bytes) -> void* {
        void* p = ws + off;
        off += bytes;
        off = (off + 255) & ~(size_t)255;
        return p;
    };
    uint16_t* wtQKVi = (uint16_t*)alloc((size_t)3072 * 1024 * 2);
    uint16_t* wtQKVt = (uint16_t*)alloc((size_t)3072 * 1024 * 2);
    uint16_t* wtPRJi = (uint16_t*)alloc((size_t)1024 * 1024 * 2);
    uint16_t* wtPRJt = (uint16_t*)alloc((size_t)1024 * 1024 * 2);
    uint16_t* wtM1i  = (uint16_t*)alloc((size_t)4096 * 1024 * 2);
    uint16_t* wtM1t  = (uint16_t*)alloc((size_t)4096 * 1024 * 2);
    uint16_t* wtM2i  = (uint16_t*)alloc((size_t)1024 * 4096 * 2);
    uint16_t* wtM2t  = (uint16_t*)alloc((size_t)1024 * 4096 * 2);
    float*    modi   = (float*)alloc(6144 * 4);
    float*    modt   = (float*)alloc(6144 * 4);
    uint16_t* xm1i   = (uint16_t*)alloc((size_t)L_IMG * HIDD * 2);
    uint16_t* xm1t   = (uint16_t*)alloc((size_t)L_TXT * HIDD * 2);
    uint16_t* qkvi   = (uint16_t*)alloc((size_t)L_IMG * 3072 * 2);
    uint16_t* qkvt   = (uint16_t*)alloc((size_t)L_TXT * 3072 * 2);
    uint16_t* Qb     = (uint16_t*)alloc((size_t)NHEAD * L_TOT * HDIM * 2);
    uint16_t* Kb     = (uint16_t*)alloc((size_t)NHEAD * L_TOT * HDIM * 2);
    uint16_t* Vb     = (uint16_t*)alloc((size_t)NHEAD * L_TOT * HDIM * 2);
    uint16_t* attn   = (uint16_t*)alloc((size_t)L_TOT * HIDD * 2);
    float*    x2i    = (float*)alloc((size_t)L_IMG * HIDD * 4);
    float*    x2t    = (float*)alloc((size_t)L_TXT * HIDD * 4);
    uint16_t* xm2i   = (uint16_t*)alloc((size_t)L_IMG * HIDD * 2);
    uint16_t* xm2t   = (uint16_t*)alloc((size_t)L_TXT * HIDD * 2);
    uint16_t* hi     = (uint16_t*)alloc((size_t)L_IMG * MLPD * 2);
    uint16_t* ht     = (uint16_t*)alloc((size_t)L_TXT * MLPD * 2);
    (void)ws_size; (void)in_sizes; (void)n_in; (void)out_size;

    // 1) weight transposes -> bf16 [N][K]
    transpose_f32_bf16<<<dim3(3072 / 64, 1024 / 64), 256, 0, stream>>>(img_qkv_w, wtQKVi, 1024, 3072);
    transpose_f32_bf16<<<dim3(3072 / 64, 1024 / 64), 256, 0, stream>>>(txt_qkv_w, wtQKVt, 1024, 3072);
    transpose_f32_bf16<<<dim3(1024 / 64, 1024 / 64), 256, 0, stream>>>(img_proj_w, wtPRJi, 1024, 1024);
    transpose_f32_bf16<<<dim3(1024 / 64, 1024 / 64), 256, 0, stream>>>(txt_proj_w, wtPRJt, 1024, 1024);
    transpose_f32_bf16<<<dim3(4096 / 64, 1024 / 64), 256, 0, stream>>>(img_mlp_w1, wtM1i, 1024, 4096);
    transpose_f32_bf16<<<dim3(4096 / 64, 1024 / 64), 256, 0, stream>>>(txt_mlp_w1, wtM1t, 1024, 4096);
    transpose_f32_bf16<<<dim3(1024 / 64, 4096 / 64), 256, 0, stream>>>(img_mlp_w2, wtM2i, 4096, 1024);
    transpose_f32_bf16<<<dim3(1024 / 64, 4096 / 64), 256, 0, stream>>>(txt_mlp_w2, wtM2t, 4096, 1024);

    // 2) modulation vectors
    mod_gemv_kernel<<<24, 256, 0, stream>>>(vec, img_mod_w, img_mod_b, modi);
    mod_gemv_kernel<<<24, 256, 0, stream>>>(vec, txt_mod_w, txt_mod_b, modt);

    // 3) LN + modulate (sh1=0, sc1=1024)
    ln_mod_kernel<<<L_IMG, 256, 0, stream>>>(img, modi, 1024, 0, xm1i);
    ln_mod_kernel<<<L_TXT, 256, 0, stream>>>(txt, modt, 1024, 0, xm1t);

    // 4) QKV GEMMs
    gemm_kernel<0><<<dim3(3072 / 128, L_IMG / 128), 256, 0, stream>>>(
        xm1i, wtQKVi, L_IMG, 3072, 1024, nullptr, nullptr, nullptr, qkvi);
    gemm_kernel<0><<<dim3(3072 / 128, L_TXT / 128), 256, 0, stream>>>(
        xm1t, wtQKVt, L_TXT, 3072, 1024, nullptr, nullptr, nullptr, qkvt);

    // 5) RMS + scatter to head-major (txt occupies seq [0,512), img [512,2560))
    rms_scatter_kernel<<<L_IMG, 256, 0, stream>>>(qkvi, L_IMG, L_TXT, img_q_s, img_k_s, Qb, Kb, Vb);
    rms_scatter_kernel<<<L_TXT, 256, 0, stream>>>(qkvt, L_TXT, 0, txt_q_s, txt_k_s, Qb, Kb, Vb);

    // 6) attention
    attn_kernel<<<dim3(L_TOT / 128, NHEAD), 256, 0, stream>>>(Qb, Kb, Vb, attn);

    // 7) proj + gate(g1@2048) + residual -> f32 x2
    gemm_kernel<2><<<dim3(1024 / 128, L_IMG / 128), 256, 0, stream>>>(
        attn + (size_t)L_TXT * HIDD, wtPRJi, L_IMG, 1024, 1024,
        img_proj_b, modi + 2048, img, x2i);
    gemm_kernel<2><<<dim3(1024 / 128, L_TXT / 128), 256, 0, stream>>>(
        attn, wtPRJt, L_TXT, 1024, 1024, txt_proj_b, modt + 2048, txt, x2t);

    // 8) LN2 + modulate (sh2=3072, sc2=4096)
    ln_mod_kernel<<<L_IMG, 256, 0, stream>>>(x2i, modi, 4096, 3072, xm2i);
    ln_mod_kernel<<<L_TXT, 256, 0, stream>>>(x2t, modt, 4096, 3072, xm2t);

    // 9) MLP1 + gelu
    gemm_kernel<1><<<dim3(MLPD / 128, L_IMG / 128), 256, 0, stream>>>(
        xm2i, wtM1i, L_IMG, MLPD, 1024, img_mlp_b1, nullptr, nullptr, hi);
    gemm_kernel<1><<<dim3(MLPD / 128, L_TXT / 128), 256, 0, stream>>>(
        xm2t, wtM1t, L_TXT, MLPD, 1024, txt_mlp_b1, nullptr, nullptr, ht);

    // 10) MLP2 + gate(g2@5120) + residual -> f32 final out
    gemm_kernel<3><<<dim3(1024 / 128, L_IMG / 128), 256, 0, stream>>>(
        hi, wtM2i, L_IMG, 1024, MLPD, img_mlp_b2, modi + 5120, x2i, out_img);
    gemm_kernel<3><<<dim3(1024 / 128, L_TXT / 128), 256, 0, stream>>>(
        ht, wtM2t, L_TXT, 1024, MLPD, txt_mlp_b2, modt + 5120, x2t, out_txt);
}

// Round 3
// 485.339 us; speedup vs baseline: 1.5904x; 1.5904x over previous
//
#include <hip/hip_runtime.h>
#include <hip/hip_bf16.h>
#include <stdint.h>

// ---------------------------------------------------------------------------
// DoubleStreamBlock (Flux MMDiT) on MI355X. IO = float32; compute bf16 MFMA.
// NH=16 HD=64 HID=1024 MLP=4096, img L=2048, txt L=512, Lattn=2560.
// ---------------------------------------------------------------------------

#define NHEAD 16
#define HDIM  64
#define HIDD  1024
#define MLPD  4096
#define L_IMG 2048
#define L_TXT 512
#define L_TOT 2560
#define EPSV  1e-6f

typedef __attribute__((ext_vector_type(8))) __bf16 bf16x8;
typedef __attribute__((ext_vector_type(4))) float  f32x4;

__device__ __forceinline__ float u2f(uint16_t u) {
    uint32_t i = (uint32_t)u << 16;
    float f; __builtin_memcpy(&f, &i, 4);
    return f;
}
__device__ __forceinline__ uint16_t f2u(float f) {
    uint32_t i; __builtin_memcpy(&i, &f, 4);
    uint32_t r = (i + 0x7fffu + ((i >> 16) & 1u)) >> 16;   // RNE
    return (uint16_t)r;
}
__device__ __forceinline__ float gelu_tanh(float x) {
    float x3 = x * x * x;
    float t  = tanhf(0.7978845608028654f * (x + 0.044715f * x3));
    return 0.5f * x * (1.f + t);
}

// ---------------------------------------------------------------------------
// Transpose + cast: f32 [K][N] -> bf16 [N][K]  (64x64 LDS tiles)
// ---------------------------------------------------------------------------
__global__ __launch_bounds__(256) void transpose_f32_bf16(const float* __restrict__ in,
                                                          uint16_t* __restrict__ out,
                                                          int K, int N) {
    __shared__ float tile[64][65];
    const int t  = threadIdx.x;
    const int c0 = blockIdx.x * 64;   // col tile (N dim)
    const int r0 = blockIdx.y * 64;   // row tile (K dim)
#pragma unroll
    for (int p = 0; p < 4; p++) {
        int row  = p * 16 + (t >> 4);
        int col4 = (t & 15) * 4;
        float4 v = *(const float4*)(in + (size_t)(r0 + row) * N + c0 + col4);
        tile[row][col4 + 0] = v.x; tile[row][col4 + 1] = v.y;
        tile[row][col4 + 2] = v.z; tile[row][col4 + 3] = v.w;
    }
    __syncthreads();
#pragma unroll
    for (int p = 0; p < 4; p++) {
        int row  = p * 16 + (t >> 4);   // output row = original col
        int col4 = (t & 15) * 4;
        ushort4 v;
        v.x = f2u(tile[col4 + 0][row]); v.y = f2u(tile[col4 + 1][row]);
        v.z = f2u(tile[col4 + 2][row]); v.w = f2u(tile[col4 + 3][row]);
        *(ushort4*)(out + (size_t)(c0 + row) * K + r0 + col4) = v;
    }
}

// ---------------------------------------------------------------------------
// Transpose V: bf16 [h][L_TOT][64] -> [h][64][L_TOT]   (64x64 tiles)
// ---------------------------------------------------------------------------
__global__ __launch_bounds__(256) void transpose_v_kernel(const uint16_t* __restrict__ Vb,
                                                          uint16_t* __restrict__ Vt) {
    __shared__ uint16_t tile[64][68];
    const int t  = threadIdx.x;
    const int p0 = blockIdx.x * 64;       // position tile
    const int h  = blockIdx.y;
    const uint16_t* src = Vb + ((size_t)h * L_TOT + p0) * HDIM;
#pragma unroll
    for (int p = 0; p < 4; p++) {
        int row = p * 16 + (t >> 4);      // position within tile
        int c4  = (t & 15) * 4;           // d
        ushort4 v = *(const ushort4*)(src + (size_t)row * HDIM + c4);
        tile[row][c4 + 0] = v.x; tile[row][c4 + 1] = v.y;
        tile[row][c4 + 2] = v.z; tile[row][c4 + 3] = v.w;
    }
    __syncthreads();
    uint16_t* dst = Vt + (size_t)h * HDIM * L_TOT;
#pragma unroll
    for (int p = 0; p < 4; p++) {
        int d  = p * 16 + (t >> 4);
        int c4 = (t & 15) * 4;            // position
        ushort4 v;
        v.x = tile[c4 + 0][d]; v.y = tile[c4 + 1][d];
        v.z = tile[c4 + 2][d]; v.w = tile[c4 + 3][d];
        *(ushort4*)(dst + (size_t)d * L_TOT + p0 + c4) = v;
    }
}

// ---------------------------------------------------------------------------
// mod GEMV: mod[j] = dot(silu(vec), W[:,j]) + b[j],  j in [0,6144)
// 96 blocks x (64 cols x 4 k-slices) for latency hiding.
// ---------------------------------------------------------------------------
__global__ __launch_bounds__(256) void mod_gemv_kernel(const float* __restrict__ vec,
                                                       const float* __restrict__ w,
                                                       const float* __restrict__ b,
                                                       float* __restrict__ mod) {
    __shared__ float s[HIDD];
    __shared__ float part[4][64];
    const int t = threadIdx.x;
    for (int i = t; i < HIDD; i += 256) {
        float x = vec[i];
        s[i] = x / (1.f + __expf(-x));
    }
    __syncthreads();
    const int col = blockIdx.x * 64 + (t & 63);
    const int ks  = t >> 6;
    float acc = 0.f;
#pragma unroll 8
    for (int k = ks * 256; k < ks * 256 + 256; k++)
        acc += s[k] * w[(size_t)k * 6144 + col];
    part[ks][t & 63] = acc;
    __syncthreads();
    if (t < 64) {
        float r = part[0][t] + part[1][t] + part[2][t] + part[3][t];
        mod[blockIdx.x * 64 + t] = r + b[blockIdx.x * 64 + t];
    }
}

// ---------------------------------------------------------------------------
// Fused LayerNorm + modulate: xm = (1+sc)*LN(x) + sh   (bf16 out, f32 in)
// ---------------------------------------------------------------------------
__global__ __launch_bounds__(256) void ln_mod_kernel(const float* __restrict__ x,
                                                     const float* __restrict__ mod,
                                                     int scOff, int shOff,
                                                     uint16_t* __restrict__ xm) {
    __shared__ float red[8];
    const int row = blockIdx.x, t = threadIdx.x;
    const size_t base = (size_t)row * HIDD + t * 4;
    float4 u = *(const float4*)(x + base);
    float v[4] = {u.x, u.y, u.z, u.w};
    float s = v[0] + v[1] + v[2] + v[3];
    float q = v[0]*v[0] + v[1]*v[1] + v[2]*v[2] + v[3]*v[3];
#pragma unroll
    for (int o = 32; o; o >>= 1) { s += __shfl_down(s, o); q += __shfl_down(q, o); }
    if ((t & 63) == 0) { red[t >> 6] = s; red[4 + (t >> 6)] = q; }
    __syncthreads();
    s = red[0] + red[1] + red[2] + red[3];
    q = red[4] + red[5] + red[6] + red[7];
    const float mu  = s * (1.f / HIDD);
    const float var = q * (1.f / HIDD) - mu * mu;
    const float rs  = rsqrtf(var + EPSV);
    ushort4 o;
    {
        int col = t * 4;
        float y0 = (v[0] - mu) * rs, y1 = (v[1] - mu) * rs;
        float y2 = (v[2] - mu) * rs, y3 = (v[3] - mu) * rs;
        o.x = f2u(y0 + mod[scOff + col + 0] * y0 + mod[shOff + col + 0]);
        o.y = f2u(y1 + mod[scOff + col + 1] * y1 + mod[shOff + col + 1]);
        o.z = f2u(y2 + mod[scOff + col + 2] * y2 + mod[shOff + col + 2]);
        o.w = f2u(y3 + mod[scOff + col + 3] * y3 + mod[shOff + col + 3]);
    }
    *(ushort4*)(xm + base) = o;
}

// ---------------------------------------------------------------------------
// Grouped m97-style bf16 GEMM (z=0: img, z=1: txt).
// C[M][N] = A[M][K] * BT[N][K]^T, 128x128 tile, BK=32.
// EPI: 0 = store bf16 | 1 = gelu(acc+bias) bf16 | 2/3 = f32 resid+gate*(acc+bias)
// ---------------------------------------------------------------------------
template <int EPI>
__global__ __launch_bounds__(256, 2) void gemm_kernel(
        const uint16_t* __restrict__ A0, const uint16_t* __restrict__ A1,
        const uint16_t* __restrict__ B0, const uint16_t* __restrict__ B1,
        int M0, int M1, int N, int K,
        const float* __restrict__ bias0, const float* __restrict__ bias1,
        const float* __restrict__ gate0, const float* __restrict__ gate1,
        const float* __restrict__ resid0, const float* __restrict__ resid1,
        void* __restrict__ C0, void* __restrict__ C1) {
    const int z = blockIdx.z;
    const int M = z ? M1 : M0;
    const int m0 = blockIdx.y * 128;
    if (m0 >= M) return;
    const uint16_t* A     = z ? A1 : A0;
    const uint16_t* BT    = z ? B1 : B0;
    const float*    bias  = z ? bias1 : bias0;
    const float*    gate  = z ? gate1 : gate0;
    const float*    resid = z ? resid1 : resid0;
    void*           C     = z ? C1 : C0;

    __shared__ uint16_t As[128 * 32];
    __shared__ uint16_t Bs[128 * 32];
    const int t = threadIdx.x;
    const int w = t >> 6, l = t & 63;
    const int lr = l & 15, lg = l >> 4;
    const int n0 = blockIdx.x * 128;
    const int srow = l >> 2, scol = (l & 3) * 8;
    const int c0 = w * 2;
    const int wr = (w >> 1) * 64, wc = (w & 1) * 64;

    const f32x4 z4 = {0.f, 0.f, 0.f, 0.f};
    f32x4 acc[4][4];
#pragma unroll
    for (int i = 0; i < 4; i++)
#pragma unroll
        for (int j = 0; j < 4; j++) acc[i][j] = z4;

    for (int kt = 0; kt < K; kt += 32) {
        __syncthreads();
#pragma unroll
        for (int i = 0; i < 2; i++) {
            const int c = c0 + i;
            const uint16_t* ga = A  + (size_t)(m0 + c * 16 + srow) * K + kt + scol;
            const uint16_t* gb = BT + (size_t)(n0 + c * 16 + srow) * K + kt + scol;
            __builtin_amdgcn_global_load_lds(
                (__attribute__((address_space(1))) void*)ga,
                (__attribute__((address_space(3))) void*)(As + c * 512), 16, 0, 0);
            __builtin_amdgcn_global_load_lds(
                (__attribute__((address_space(1))) void*)gb,
                (__attribute__((address_space(3))) void*)(Bs + c * 512), 16, 0, 0);
        }
        __syncthreads();
        bf16x8 af[4], bfr[4];
#pragma unroll
        for (int mi = 0; mi < 4; mi++)
            af[mi] = *(const bf16x8*)(As + (wr + mi * 16 + lr) * 32 + lg * 8);
#pragma unroll
        for (int nj = 0; nj < 4; nj++)
            bfr[nj] = *(const bf16x8*)(Bs + (wc + nj * 16 + lr) * 32 + lg * 8);
#pragma unroll
        for (int mi = 0; mi < 4; mi++)
#pragma unroll
            for (int nj = 0; nj < 4; nj++)
                acc[mi][nj] = __builtin_amdgcn_mfma_f32_16x16x32_bf16(
                    af[mi], bfr[nj], acc[mi][nj], 0, 0, 0);
    }

#pragma unroll
    for (int mi = 0; mi < 4; mi++)
#pragma unroll
        for (int nj = 0; nj < 4; nj++) {
            const int col = n0 + wc + nj * 16 + lr;
            float bv = 0.f, gv = 0.f;
            if (EPI != 0) bv = bias[col];
            if (EPI == 2 || EPI == 3) gv = gate[col];
#pragma unroll
            for (int j = 0; j < 4; j++) {
                const int row = m0 + wr + mi * 16 + lg * 4 + j;
                const size_t idx = (size_t)row * N + col;
                float v = acc[mi][nj][j];
                if (EPI == 0) {
                    ((uint16_t*)C)[idx] = f2u(v);
                } else if (EPI == 1) {
                    ((uint16_t*)C)[idx] = f2u(gelu_tanh(v + bv));
                } else {
                    ((float*)C)[idx] = resid[idx] + gv * (v + bv);
                }
            }
        }
}

// ---------------------------------------------------------------------------
// RMS-norm q,k (per head of 64) + scatter qkv row -> head-major Q/K/V (bf16).
// Q gets the 1/sqrt(HD)=0.125 attention scale folded in.
// ---------------------------------------------------------------------------
__global__ __launch_bounds__(256) void rms_scatter_kernel(
        const uint16_t* __restrict__ qkv, int L, int glOff,
        const float* __restrict__ qs, const float* __restrict__ ks,
        uint16_t* __restrict__ Q, uint16_t* __restrict__ Kb, uint16_t* __restrict__ V) {
    const int row = blockIdx.x;
    const int t = threadIdx.x;
    const int head = t >> 4, d0 = (t & 15) * 4;
    const uint16_t* base = qkv + (size_t)row * 3072;
    const size_t obase = ((size_t)head * L_TOT + (glOff + row)) * HDIM + d0;
    // Q
    {
        ushort4 u = *(const ushort4*)(base + head * HDIM + d0);
        float v0 = u2f(u.x), v1 = u2f(u.y), v2 = u2f(u.z), v3 = u2f(u.w);
        float ss = v0*v0 + v1*v1 + v2*v2 + v3*v3;
        ss += __shfl_xor(ss, 1); ss += __shfl_xor(ss, 2);
        ss += __shfl_xor(ss, 4); ss += __shfl_xor(ss, 8);
        float inv = rsqrtf(ss * (1.f / HDIM) + EPSV) * 0.125f;
        ushort4 o;
        o.x = f2u(v0 * inv * qs[d0 + 0]);
        o.y = f2u(v1 * inv * qs[d0 + 1]);
        o.z = f2u(v2 * inv * qs[d0 + 2]);
        o.w = f2u(v3 * inv * qs[d0 + 3]);
        *(ushort4*)(Q + obase) = o;
    }
    // K
    {
        ushort4 u = *(const ushort4*)(base + HIDD + head * HDIM + d0);
        float v0 = u2f(u.x), v1 = u2f(u.y), v2 = u2f(u.z), v3 = u2f(u.w);
        float ss = v0*v0 + v1*v1 + v2*v2 + v3*v3;
        ss += __shfl_xor(ss, 1); ss += __shfl_xor(ss, 2);
        ss += __shfl_xor(ss, 4); ss += __shfl_xor(ss, 8);
        float inv = rsqrtf(ss * (1.f / HDIM) + EPSV);
        ushort4 o;
        o.x = f2u(v0 * inv * ks[d0 + 0]);
        o.y = f2u(v1 * inv * ks[d0 + 1]);
        o.z = f2u(v2 * inv * ks[d0 + 2]);
        o.w = f2u(v3 * inv * ks[d0 + 3]);
        *(ushort4*)(Kb + obase) = o;
    }
    // V (passthrough)
    {
        ushort4 u = *(const ushort4*)(base + 2 * HIDD + head * HDIM + d0);
        *(ushort4*)(V + obase) = u;
    }
}

// ---------------------------------------------------------------------------
// Flash attention: block = 4 waves x 32 q-rows, 32-key tiles, online softmax.
// Q/K head-major [h][L_TOT][64]; V TRANSPOSED [h][64][L_TOT] (all bf16).
// Q pre-scaled by 0.125. out: [L_TOT][1024] bf16.
// ---------------------------------------------------------------------------
__global__ __launch_bounds__(256) void attn_kernel(const uint16_t* __restrict__ Q,
                                                   const uint16_t* __restrict__ Kg,
                                                   const uint16_t* __restrict__ Vt,
                                                   uint16_t* __restrict__ out) {
    __shared__ __align__(16) uint16_t P[4][32][40];   // padded: 80B rows, 2-way banks
    const int t = threadIdx.x;
    const int w = t >> 6, l = t & 63;
    const int lr = l & 15, lg = l >> 4;
    const int h = blockIdx.y;
    const int q0 = blockIdx.x * 128 + w * 32;
    const uint16_t* Qh = Q  + (size_t)h * L_TOT * HDIM;
    const uint16_t* Kh = Kg + (size_t)h * L_TOT * HDIM;
    const uint16_t* Vh = Vt + (size_t)h * HDIM * L_TOT;

    bf16x8 qf[2][2];
#pragma unroll
    for (int mi = 0; mi < 2; mi++)
#pragma unroll
        for (int ks = 0; ks < 2; ks++)
            qf[mi][ks] = *(const bf16x8*)(Qh + (size_t)(q0 + mi * 16 + lr) * HDIM + ks * 32 + lg * 8);

    const f32x4 z4 = {0.f, 0.f, 0.f, 0.f};
    f32x4 of[2][4];
    float mrun[2][4], lrun[2][4];
#pragma unroll
    for (int mi = 0; mi < 2; mi++) {
#pragma unroll
        for (int nj = 0; nj < 4; nj++) of[mi][nj] = z4;
#pragma unroll
        for (int j = 0; j < 4; j++) { mrun[mi][j] = -1e30f; lrun[mi][j] = 0.f; }
    }

    for (int k0 = 0; k0 < L_TOT; k0 += 32) {
        f32x4 sf[2][2];
        sf[0][0] = z4; sf[0][1] = z4; sf[1][0] = z4; sf[1][1] = z4;
#pragma unroll
        for (int nj = 0; nj < 2; nj++)
#pragma unroll
            for (int ks = 0; ks < 2; ks++) {
                bf16x8 kf = *(const bf16x8*)(Kh + (size_t)(k0 + nj * 16 + lr) * HDIM + ks * 32 + lg * 8);
                sf[0][nj] = __builtin_amdgcn_mfma_f32_16x16x32_bf16(qf[0][ks], kf, sf[0][nj], 0, 0, 0);
                sf[1][nj] = __builtin_amdgcn_mfma_f32_16x16x32_bf16(qf[1][ks], kf, sf[1][nj], 0, 0, 0);
            }
        // V fragments for this tile: contiguous thanks to transposed layout
        bf16x8 vf[4];
#pragma unroll
        for (int nj = 0; nj < 4; nj++)
            vf[nj] = *(const bf16x8*)(Vh + (size_t)(nj * 16 + lr) * L_TOT + k0 + lg * 8);
#pragma unroll
        for (int mi = 0; mi < 2; mi++) {
            float mt[4], corr[4], p0[4], p1[4], rs[4];
#pragma unroll
            for (int j = 0; j < 4; j++) mt[j] = fmaxf(sf[mi][0][j], sf[mi][1][j]);
#pragma unroll
            for (int o = 8; o; o >>= 1) {
#pragma unroll
                for (int j = 0; j < 4; j++) mt[j] = fmaxf(mt[j], __shfl_xor(mt[j], o));
            }
#pragma unroll
            for (int j = 0; j < 4; j++) {
                float mn = fmaxf(mrun[mi][j], mt[j]);
                corr[j] = __expf(mrun[mi][j] - mn);
                mrun[mi][j] = mn;
                p0[j] = __expf(sf[mi][0][j] - mn);
                p1[j] = __expf(sf[mi][1][j] - mn);
                rs[j] = p0[j] + p1[j];
            }
#pragma unroll
            for (int o = 8; o; o >>= 1) {
#pragma unroll
                for (int j = 0; j < 4; j++) rs[j] += __shfl_xor(rs[j], o);
            }
#pragma unroll
            for (int j = 0; j < 4; j++) lrun[mi][j] = lrun[mi][j] * corr[j] + rs[j];
#pragma unroll
            for (int nj = 0; nj < 4; nj++)
#pragma unroll
                for (int j = 0; j < 4; j++) of[mi][nj][j] *= corr[j];
#pragma unroll
            for (int j = 0; j < 4; j++) {
                P[w][mi * 16 + lg * 4 + j][lr]      = f2u(p0[j]);
                P[w][mi * 16 + lg * 4 + j][16 + lr] = f2u(p1[j]);
            }
        }
        bf16x8 pa0 = *(const bf16x8*)&P[w][lr][lg * 8];
        bf16x8 pa1 = *(const bf16x8*)&P[w][16 + lr][lg * 8];
#pragma unroll
        for (int nj = 0; nj < 4; nj++) {
            of[0][nj] = __builtin_amdgcn_mfma_f32_16x16x32_bf16(pa0, vf[nj], of[0][nj], 0, 0, 0);
            of[1][nj] = __builtin_amdgcn_mfma_f32_16x16x32_bf16(pa1, vf[nj], of[1][nj], 0, 0, 0);
        }
    }
#pragma unroll
    for (int mi = 0; mi < 2; mi++)
#pragma unroll
        for (int j = 0; j < 4; j++) {
            float inv = 1.f / lrun[mi][j];
            size_t rbase = (size_t)(q0 + mi * 16 + lg * 4 + j) * HIDD + h * HDIM;
#pragma unroll
            for (int nj = 0; nj < 4; nj++)
                out[rbase + nj * 16 + lr] = f2u(of[mi][nj][j] * inv);
        }
}

// ---------------------------------------------------------------------------
// host launcher
// ---------------------------------------------------------------------------
extern "C" void kernel_launch(void* const* d_in, const int* in_sizes, int n_in,
                              void* d_out, int out_size, void* d_ws, size_t ws_size,
                              hipStream_t stream) {
    const float* img        = (const float*)d_in[0];
    const float* txt        = (const float*)d_in[1];
    const float* vec        = (const float*)d_in[2];
    const float* img_mod_w  = (const float*)d_in[3];
    const float* img_mod_b  = (const float*)d_in[4];
    const float* txt_mod_w  = (const float*)d_in[5];
    const float* txt_mod_b  = (const float*)d_in[6];
    const float* img_qkv_w  = (const float*)d_in[7];
    const float* img_q_s    = (const float*)d_in[8];
    const float* img_k_s    = (const float*)d_in[9];
    const float* img_proj_w = (const float*)d_in[10];
    const float* img_proj_b = (const float*)d_in[11];
    const float* img_mlp_w1 = (const float*)d_in[12];
    const float* img_mlp_b1 = (const float*)d_in[13];
    const float* img_mlp_w2 = (const float*)d_in[14];
    const float* img_mlp_b2 = (const float*)d_in[15];
    const float* txt_qkv_w  = (const float*)d_in[16];
    const float* txt_q_s    = (const float*)d_in[17];
    const float* txt_k_s    = (const float*)d_in[18];
    const float* txt_proj_w = (const float*)d_in[19];
    const float* txt_proj_b = (const float*)d_in[20];
    const float* txt_mlp_w1 = (const float*)d_in[21];
    const float* txt_mlp_b1 = (const float*)d_in[22];
    const float* txt_mlp_w2 = (const float*)d_in[23];
    const float* txt_mlp_b2 = (const float*)d_in[24];

    float* out_img = (float*)d_out;
    float* out_txt = out_img + (size_t)L_IMG * HIDD;

    char* ws = (char*)d_ws;
    size_t off = 0;
    auto alloc = [&](size_t bytes) -> void* {
        void* p = ws + off;
        off += bytes;
        off = (off + 255) & ~(size_t)255;
        return p;
    };
    uint16_t* wtQKVi = (uint16_t*)alloc((size_t)3072 * 1024 * 2);
    uint16_t* wtQKVt = (uint16_t*)alloc((size_t)3072 * 1024 * 2);
    uint16_t* wtPRJi = (uint16_t*)alloc((size_t)1024 * 1024 * 2);
    uint16_t* wtPRJt = (uint16_t*)alloc((size_t)1024 * 1024 * 2);
    uint16_t* wtM1i  = (uint16_t*)alloc((size_t)4096 * 1024 * 2);
    uint16_t* wtM1t  = (uint16_t*)alloc((size_t)4096 * 1024 * 2);
    uint16_t* wtM2i  = (uint16_t*)alloc((size_t)1024 * 4096 * 2);
    uint16_t* wtM2t  = (uint16_t*)alloc((size_t)1024 * 4096 * 2);
    float*    modi   = (float*)alloc(6144 * 4);
    float*    modt   = (float*)alloc(6144 * 4);
    uint16_t* xm1i   = (uint16_t*)alloc((size_t)L_IMG * HIDD * 2);
    uint16_t* xm1t   = (uint16_t*)alloc((size_t)L_TXT * HIDD * 2);
    uint16_t* qkvi   = (uint16_t*)alloc((size_t)L_IMG * 3072 * 2);
    uint16_t* qkvt   = (uint16_t*)alloc((size_t)L_TXT * 3072 * 2);
    uint16_t* Qb     = (uint16_t*)alloc((size_t)NHEAD * L_TOT * HDIM * 2);
    uint16_t* Kb     = (uint16_t*)alloc((size_t)NHEAD * L_TOT * HDIM * 2);
    uint16_t* Vb     = (uint16_t*)alloc((size_t)NHEAD * L_TOT * HDIM * 2);
    uint16_t* Vtb    = (uint16_t*)alloc((size_t)NHEAD * L_TOT * HDIM * 2);
    uint16_t* attn   = (uint16_t*)alloc((size_t)L_TOT * HIDD * 2);
    float*    x2i    = (float*)alloc((size_t)L_IMG * HIDD * 4);
    float*    x2t    = (float*)alloc((size_t)L_TXT * HIDD * 4);
    uint16_t* xm2i   = (uint16_t*)alloc((size_t)L_IMG * HIDD * 2);
    uint16_t* xm2t   = (uint16_t*)alloc((size_t)L_TXT * HIDD * 2);
    uint16_t* hi     = (uint16_t*)alloc((size_t)L_IMG * MLPD * 2);
    uint16_t* ht     = (uint16_t*)alloc((size_t)L_TXT * MLPD * 2);
    (void)ws_size; (void)in_sizes; (void)n_in; (void)out_size;

    // 1) weight transposes -> bf16 [N][K]
    transpose_f32_bf16<<<dim3(3072 / 64, 1024 / 64), 256, 0, stream>>>(img_qkv_w, wtQKVi, 1024, 3072);
    transpose_f32_bf16<<<dim3(3072 / 64, 1024 / 64), 256, 0, stream>>>(txt_qkv_w, wtQKVt, 1024, 3072);
    transpose_f32_bf16<<<dim3(1024 / 64, 1024 / 64), 256, 0, stream>>>(img_proj_w, wtPRJi, 1024, 1024);
    transpose_f32_bf16<<<dim3(1024 / 64, 1024 / 64), 256, 0, stream>>>(txt_proj_w, wtPRJt, 1024, 1024);
    transpose_f32_bf16<<<dim3(4096 / 64, 1024 / 64), 256, 0, stream>>>(img_mlp_w1, wtM1i, 1024, 4096);
    transpose_f32_bf16<<<dim3(4096 / 64, 1024 / 64), 256, 0, stream>>>(txt_mlp_w1, wtM1t, 1024, 4096);
    transpose_f32_bf16<<<dim3(1024 / 64, 4096 / 64), 256, 0, stream>>>(img_mlp_w2, wtM2i, 4096, 1024);
    transpose_f32_bf16<<<dim3(1024 / 64, 4096 / 64), 256, 0, stream>>>(txt_mlp_w2, wtM2t, 4096, 1024);

    // 2) modulation vectors
    mod_gemv_kernel<<<96, 256, 0, stream>>>(vec, img_mod_w, img_mod_b, modi);
    mod_gemv_kernel<<<96, 256, 0, stream>>>(vec, txt_mod_w, txt_mod_b, modt);

    // 3) LN + modulate (sh1=0, sc1=1024)
    ln_mod_kernel<<<L_IMG, 256, 0, stream>>>(img, modi, 1024, 0, xm1i);
    ln_mod_kernel<<<L_TXT, 256, 0, stream>>>(txt, modt, 1024, 0, xm1t);

    // 4) QKV GEMMs (grouped img+txt)
    gemm_kernel<0><<<dim3(3072 / 128, L_IMG / 128, 2), 256, 0, stream>>>(
        xm1i, xm1t, wtQKVi, wtQKVt, L_IMG, L_TXT, 3072, 1024,
        nullptr, nullptr, nullptr, nullptr, nullptr, nullptr, qkvi, qkvt);

    // 5) RMS + scatter to head-major (txt at seq [0,512), img at [512,2560))
    rms_scatter_kernel<<<L_IMG, 256, 0, stream>>>(qkvi, L_IMG, L_TXT, img_q_s, img_k_s, Qb, Kb, Vb);
    rms_scatter_kernel<<<L_TXT, 256, 0, stream>>>(qkvt, L_TXT, 0, txt_q_s, txt_k_s, Qb, Kb, Vb);

    // 5b) V transpose -> [h][64][L_TOT]
    transpose_v_kernel<<<dim3(L_TOT / 64, NHEAD), 256, 0, stream>>>(Vb, Vtb);

    // 6) attention
    attn_kernel<<<dim3(L_TOT / 128, NHEAD), 256, 0, stream>>>(Qb, Kb, Vtb, attn);

    // 7) proj + gate(g1@2048) + residual -> f32 x2 (grouped)
    gemm_kernel<2><<<dim3(1024 / 128, L_IMG / 128, 2), 256, 0, stream>>>(
        attn + (size_t)L_TXT * HIDD, attn, wtPRJi, wtPRJt, L_IMG, L_TXT, 1024, 1024,
        img_proj_b, txt_proj_b, modi + 2048, modt + 2048, img, txt, x2i, x2t);

    // 8) LN2 + modulate (sh2=3072, sc2=4096)
    ln_mod_kernel<<<L_IMG, 256, 0, stream>>>(x2i, modi, 4096, 3072, xm2i);
    ln_mod_kernel<<<L_TXT, 256, 0, stream>>>(x2t, modt, 4096, 3072, xm2t);

    // 9) MLP1 + gelu (grouped)
    gemm_kernel<1><<<dim3(MLPD / 128, L_IMG / 128, 2), 256, 0, stream>>>(
        xm2i, xm2t, wtM1i, wtM1t, L_IMG, L_TXT, MLPD, 1024,
        img_mlp_b1, txt_mlp_b1, nullptr, nullptr, nullptr, nullptr, hi, ht);

    // 10) MLP2 + gate(g2@5120) + residual -> f32 final out (grouped)
    gemm_kernel<3><<<dim3(1024 / 128, L_IMG / 128, 2), 256, 0, stream>>>(
        hi, ht, wtM2i, wtM2t, L_IMG, L_TXT, 1024, MLPD,
        img_mlp_b2, txt_mlp_b2, modi + 5120, modt + 5120, x2i, x2t, out_img, out_txt);
}